// Round 1
// baseline (750.837 us; speedup 1.0000x reference)
//
#include <hip/hip_runtime.h>
#include <math.h>

#define T_TOKENS 32768
#define DIM 2048
#define N_EXPERTS 256
#define N_GROUPS 8
#define EPG 32
#define TOPK 8
#define TOPK_GROUPS 4
#define ROUTE_SCALE 2.5f

#define BM 128          // tokens per block
#define BK 32           // K-tile
#define KP 40           // padded LDS row (fp16 elems): 80B row -> conflict-free b128
#define KITERS (DIM / BK)
#define W_SCALE 256.0f  // pre-scale W so w_lo stays normal in fp16
#define INV_W_SCALE (1.0f / 256.0f)

typedef unsigned short u16;
typedef _Float16 f16x8 __attribute__((ext_vector_type(8)));
typedef float f32x4 __attribute__((ext_vector_type(4)));

__device__ __forceinline__ u16 f16_bits(_Float16 h) {
    union { _Float16 f; u16 u; } c; c.f = h; return c.u;
}

// ---------------------------------------------------------------------------
// Kernel 1: split 256*W (fp32) into fp16 hi/lo planes. 2 MB, L2-resident.
// fp16 pair captures 22+ mantissa bits; x*w' products are exact in fp32.
// ---------------------------------------------------------------------------
__global__ __launch_bounds__(256) void convert_w(
    const float* __restrict__ W, u16* __restrict__ Whi, u16* __restrict__ Wlo)
{
    const int i = blockIdx.x * 256 + threadIdx.x;   // 524288 total
    const float x = W[i] * W_SCALE;
    const _Float16 hi = (_Float16)x;
    const _Float16 lo = (_Float16)(x - (float)hi);
    Whi[i] = f16_bits(hi);
    Wlo[i] = f16_bits(lo);
}

// ---------------------------------------------------------------------------
// Kernel 2: fused  sigmoid(X @ W^T) + bias  ->  group-limited top-k routing.
// Block: 512 thr (8 waves, wave grid 2m x 4n), tile 128 tokens x 256 experts.
// Split-fp16 3-term MFMA (hh + hl + lh): logit error ~1e-7, fp32 class.
// Scores live only in LDS (64KB union with staging); routing fused in epilogue.
// ---------------------------------------------------------------------------
__global__ __launch_bounds__(512, 2) void fused_gate(
    const float* __restrict__ X,
    const u16* __restrict__ Whi, const u16* __restrict__ Wlo,
    const float* __restrict__ bias,
    float* __restrict__ out_w, float* __restrict__ out_i)
{
    __shared__ __align__(16) char smem[65536];
    u16* Ahi = (u16*)smem;            // [128][KP]   10240 B
    u16* Alo = Ahi + BM * KP;         // [128][KP]   10240 B
    u16* Bhi = Alo + BM * KP;         // [256][KP]   20480 B
    u16* Blo = Bhi + N_EXPERTS * KP;  // [256][KP]   20480 B  (total 61440)
    float* Sc = (float*)smem;         // epilogue alias: [64][256] fp32 = 65536 B

    const int tid = threadIdx.x;
    const int m0 = blockIdx.x * BM;

    // --- staging assignment ---
    const int ar = tid >> 3;          // X row 0..63 (and +64)
    const int ac = (tid & 7) * 4;     // k offset (floats), 8 lanes cover 32 k
    const int br = tid >> 2;          // W row 0..127 (and +128)
    const int bc = (tid & 3) * 8;     // k offset (fp16), 4 lanes cover 32 k

    const float* xa = X + (size_t)(m0 + ar) * DIM + ac;
    const float* xb = X + (size_t)(m0 + ar + 64) * DIM + ac;
    const u16* wh0 = Whi + br * DIM + bc;
    const u16* wh1 = Whi + (br + 128) * DIM + bc;
    const u16* wl0 = Wlo + br * DIM + bc;
    const u16* wl1 = Wlo + (br + 128) * DIM + bc;

    // --- wave / fragment assignment ---
    const int lane = tid & 63;
    const int wave = tid >> 6;
    const int wm = wave >> 2;         // 0..1: token half
    const int wn = wave & 3;          // 0..3: expert quarter
    const int l16 = lane & 15;
    const int quad = lane >> 4;

    f32x4 acc[4][4];
    #pragma unroll
    for (int i = 0; i < 4; i++)
        #pragma unroll
        for (int j = 0; j < 4; j++) acc[i][j] = (f32x4){0.f, 0.f, 0.f, 0.f};

    // prefetch tile 0 into registers
    float4 a0 = *(const float4*)(xa);
    float4 a1 = *(const float4*)(xb);
    uint4 h0 = *(const uint4*)(wh0);
    uint4 h1 = *(const uint4*)(wh1);
    uint4 l0 = *(const uint4*)(wl0);
    uint4 l1 = *(const uint4*)(wl1);

    for (int it = 0; it < KITERS; ++it) {
        __syncthreads();   // all waves done reading LDS of previous tile
        // --- split A (fp32 -> fp16 hi/lo) + store; store B planes ---
        {
            ushort4 h, l;
            _Float16 t;
            t = (_Float16)a0.x; h.x = f16_bits(t); l.x = f16_bits((_Float16)(a0.x - (float)t));
            t = (_Float16)a0.y; h.y = f16_bits(t); l.y = f16_bits((_Float16)(a0.y - (float)t));
            t = (_Float16)a0.z; h.z = f16_bits(t); l.z = f16_bits((_Float16)(a0.z - (float)t));
            t = (_Float16)a0.w; h.w = f16_bits(t); l.w = f16_bits((_Float16)(a0.w - (float)t));
            *(ushort4*)&Ahi[ar * KP + ac] = h;
            *(ushort4*)&Alo[ar * KP + ac] = l;
            t = (_Float16)a1.x; h.x = f16_bits(t); l.x = f16_bits((_Float16)(a1.x - (float)t));
            t = (_Float16)a1.y; h.y = f16_bits(t); l.y = f16_bits((_Float16)(a1.y - (float)t));
            t = (_Float16)a1.z; h.z = f16_bits(t); l.z = f16_bits((_Float16)(a1.z - (float)t));
            t = (_Float16)a1.w; h.w = f16_bits(t); l.w = f16_bits((_Float16)(a1.w - (float)t));
            *(ushort4*)&Ahi[(ar + 64) * KP + ac] = h;
            *(ushort4*)&Alo[(ar + 64) * KP + ac] = l;
        }
        *(uint4*)&Bhi[br * KP + bc] = h0;
        *(uint4*)&Bhi[(br + 128) * KP + bc] = h1;
        *(uint4*)&Blo[br * KP + bc] = l0;
        *(uint4*)&Blo[(br + 128) * KP + bc] = l1;
        __syncthreads();

        // --- prefetch next tile (hidden under ~2000-cyc MFMA section) ---
        if (it + 1 < KITERS) {
            const int ko = (it + 1) * BK;
            a0 = *(const float4*)(xa + ko);
            a1 = *(const float4*)(xb + ko);
            h0 = *(const uint4*)(wh0 + ko);
            h1 = *(const uint4*)(wh1 + ko);
            l0 = *(const uint4*)(wl0 + ko);
            l1 = *(const uint4*)(wl1 + ko);
        }

        // --- LDS -> fragments (ds_read_b128, 80B row stride: 2-way = free) ---
        f16x8 fah[4], fal[4], fbh[4], fbl[4];
        #pragma unroll
        for (int i = 0; i < 4; i++) {
            const int mrow = wm * 64 + i * 16 + l16;
            fah[i] = *(const f16x8*)&Ahi[mrow * KP + quad * 8];
            fal[i] = *(const f16x8*)&Alo[mrow * KP + quad * 8];
            const int nrow = wn * 64 + i * 16 + l16;
            fbh[i] = *(const f16x8*)&Bhi[nrow * KP + quad * 8];
            fbl[i] = *(const f16x8*)&Blo[nrow * KP + quad * 8];
        }
        // --- 3-term split-fp16 MFMA: hh + hl + lh (ll term is O(2^-24)) ---
        #pragma unroll
        for (int i = 0; i < 4; i++)
            #pragma unroll
            for (int j = 0; j < 4; j++) {
                acc[i][j] = __builtin_amdgcn_mfma_f32_16x16x32_f16(fah[i], fbh[j], acc[i][j], 0, 0, 0);
                acc[i][j] = __builtin_amdgcn_mfma_f32_16x16x32_f16(fah[i], fbl[j], acc[i][j], 0, 0, 0);
                acc[i][j] = __builtin_amdgcn_mfma_f32_16x16x32_f16(fal[i], fbh[j], acc[i][j], 0, 0, 0);
            }
    }

    // --- epilogue: biased sigmoid scores -> LDS, then fused routing ---
    float bv[4];
    #pragma unroll
    for (int j = 0; j < 4; j++) bv[j] = bias[wn * 64 + j * 16 + l16];

    for (int pass = 0; pass < 2; ++pass) {
        __syncthreads();   // staging reads (p0) / prev routing (p1) complete
        if (wm == pass) {  // wave-uniform: 4 waves own these 64 token rows
            #pragma unroll
            for (int i = 0; i < 4; i++)
                #pragma unroll
                for (int j = 0; j < 4; j++)
                    #pragma unroll
                    for (int r = 0; r < 4; r++) {
                        const int trow = i * 16 + quad * 4 + r;          // 0..63
                        const int e = wn * 64 + j * 16 + l16;            // 0..255
                        const float logit = acc[i][j][r] * INV_W_SCALE;
                        const float s = 1.f / (1.f + expf(-logit));
                        Sc[trow * N_EXPERTS + e] = s + bv[j];            // BIASED
                    }
        }
        __syncthreads();

        if (tid < 64) {    // one wave routes 64 tokens; lane-staggered LDS reads
            const float* row = Sc + tid * N_EXPERTS;

            // group score = sum of top-2 biased (matches jax order: m1+m2)
            float gs[N_GROUPS];
            #pragma unroll
            for (int g = 0; g < N_GROUPS; g++) {
                float m1 = -INFINITY, m2 = -INFINITY;
                #pragma unroll
                for (int jj = 0; jj < EPG; jj++) {
                    const float v = row[g * EPG + ((tid + jj) & (EPG - 1))];
                    if (v > m1) { m2 = m1; m1 = v; }
                    else if (v > m2) { m2 = v; }
                }
                gs[g] = m1 + m2;
            }
            // keep top-4 groups (jax tie-break: lower index wins)
            unsigned keep = 0;
            #pragma unroll
            for (int g = 0; g < N_GROUPS; g++) {
                int cnt = 0;
                #pragma unroll
                for (int h = 0; h < N_GROUPS; h++)
                    if (gs[h] > gs[g] || (gs[h] == gs[g] && h < g)) cnt++;
                if (cnt < TOPK_GROUPS) keep |= (1u << g);
            }
            // top-8 experts within kept groups; comparator (v desc, idx asc)
            // makes result independent of staggered scan order
            float tv[TOPK]; int ti[TOPK];
            #pragma unroll
            for (int i = 0; i < TOPK; i++) { tv[i] = -INFINITY; ti[i] = 0x7fffffff; }
            for (int g = 0; g < N_GROUPS; g++) {
                if (!(keep & (1u << g))) continue;
                #pragma unroll 4
                for (int jj = 0; jj < EPG; jj++) {
                    const int e = g * EPG + ((tid + jj) & (EPG - 1));
                    const float v = row[e];
                    if (v > tv[TOPK - 1] || (v == tv[TOPK - 1] && e < ti[TOPK - 1])) {
                        float cv = v; int ce = e;
                        #pragma unroll
                        for (int s = 0; s < TOPK; s++) {
                            const bool b = (cv > tv[s]) || (cv == tv[s] && ce < ti[s]);
                            if (b) {
                                const float t1 = tv[s]; tv[s] = cv; cv = t1;
                                const int t2 = ti[s]; ti[s] = ce; ce = t2;
                            }
                        }
                    }
                }
            }
            // weights from RAW scores (biased - bias), normalize, scale
            float w[TOPK], sum = 0.f;
            #pragma unroll
            for (int i = 0; i < TOPK; i++) {
                w[i] = row[ti[i]] - bias[ti[i]];
                sum += w[i];
            }
            const float scale = ROUTE_SCALE / fmaxf(sum, 1e-10f);
            const size_t t = (size_t)m0 + pass * 64 + tid;
            #pragma unroll
            for (int i = 0; i < TOPK; i++) {
                out_w[t * TOPK + i] = w[i] * scale;
                out_i[t * TOPK + i] = (float)ti[i];
            }
        }
    }
}

extern "C" void kernel_launch(void* const* d_in, const int* in_sizes, int n_in,
                              void* d_out, int out_size, void* d_ws, size_t ws_size,
                              hipStream_t stream)
{
    const float* x = (const float*)d_in[0];     // (T, D)
    const float* w = (const float*)d_in[1];     // (E, D)
    const float* b = (const float*)d_in[2];     // (E,)

    u16* whi = (u16*)d_ws;                      // (E, D) fp16 hi plane, 1 MB
    u16* wlo = whi + (size_t)N_EXPERTS * DIM;   // (E, D) fp16 lo plane, 1 MB

    float* out_w = (float*)d_out;                              // (T, 8)
    float* out_i = (float*)d_out + (size_t)T_TOKENS * TOPK;    // (T, 8) as fp32

    convert_w<<<(N_EXPERTS * DIM) / 256, 256, 0, stream>>>(w, whi, wlo);
    fused_gate<<<T_TOKENS / BM, 512, 0, stream>>>(x, whi, wlo, b, out_w, out_i);
}

// Round 2
// 604.602 us; speedup vs baseline: 1.2419x; 1.2419x over previous
//
#include <hip/hip_runtime.h>
#include <math.h>

#define T_TOKENS 32768
#define DIM 2048
#define N_EXPERTS 256
#define N_GROUPS 8
#define EPG 32
#define TOPK 8
#define TOPK_GROUPS 4
#define ROUTE_SCALE 2.5f

#define BM 64           // tokens per block (was 128): grid 512 -> all 256 CUs busy at 2 blocks/CU
#define BK 32           // K-tile
#define KP 40           // padded LDS row (fp16 elems): 80B row -> near-conflict-free b128
#define KITERS (DIM / BK)
#define W_SCALE 256.0f  // pre-scale W so w_lo stays normal in fp16
#define INV_W_SCALE (1.0f / 256.0f)

typedef unsigned short u16;
typedef _Float16 f16x8 __attribute__((ext_vector_type(8)));
typedef float f32x4 __attribute__((ext_vector_type(4)));

__device__ __forceinline__ u16 f16_bits(_Float16 h) {
    union { _Float16 f; u16 u; } c; c.f = h; return c.u;
}

// ---------------------------------------------------------------------------
// Kernel 1: split 256*W (fp32) into fp16 hi/lo planes. 2 MB, L2-resident.
// ---------------------------------------------------------------------------
__global__ __launch_bounds__(256) void convert_w(
    const float* __restrict__ W, u16* __restrict__ Whi, u16* __restrict__ Wlo)
{
    const int i = blockIdx.x * 256 + threadIdx.x;   // 524288 total
    const float x = W[i] * W_SCALE;
    const _Float16 hi = (_Float16)x;
    const _Float16 lo = (_Float16)(x - (float)hi);
    Whi[i] = f16_bits(hi);
    Wlo[i] = f16_bits(lo);
}

// ---------------------------------------------------------------------------
// Kernel 2: fused  sigmoid(X @ W^T) + bias  ->  group-limited top-k routing.
// Block: 512 thr (8 waves, wave grid 2m x 4n), tile 64 tokens x 256 experts.
// Grid 512 blocks -> 2 blocks/CU on all 256 CUs: two independent barrier
// groups per CU hide each other's barrier-drain stalls (R1 fix: R0 packed
// 2x128-token blocks onto ~half the CUs, leaving the rest idle).
// Split-fp16 3-term MFMA (hh + hl + lh): logit error ~1e-7, fp32 class.
// ---------------------------------------------------------------------------
__global__ __launch_bounds__(512, 4) void fused_gate(
    const float* __restrict__ X,
    const u16* __restrict__ Whi, const u16* __restrict__ Wlo,
    const float* __restrict__ bias,
    float* __restrict__ out_w, float* __restrict__ out_i)
{
    __shared__ __align__(16) char smem[65536];
    u16* Ahi = (u16*)smem;            // [64][KP]    5120 B
    u16* Alo = Ahi + BM * KP;         // [64][KP]    5120 B
    u16* Bhi = Alo + BM * KP;         // [256][KP]  20480 B
    u16* Blo = Bhi + N_EXPERTS * KP;  // [256][KP]  20480 B  (total 51200)
    float* Sc = (float*)smem;         // epilogue alias: [64][256] fp32 = 65536 B

    const int tid = threadIdx.x;
    const int m0 = blockIdx.x * BM;

    // --- staging assignment ---
    const int ar = tid >> 3;          // X row 0..63
    const int ac = (tid & 7) * 4;     // k offset (floats), 8 lanes cover 32 k
    const int br = tid >> 2;          // W row 0..127 (and +128)
    const int bc = (tid & 3) * 8;     // k offset (fp16), 4 lanes cover 32 k

    const float* xa = X + (size_t)(m0 + ar) * DIM + ac;
    const u16* wh0 = Whi + br * DIM + bc;
    const u16* wh1 = Whi + (br + 128) * DIM + bc;
    const u16* wl0 = Wlo + br * DIM + bc;
    const u16* wl1 = Wlo + (br + 128) * DIM + bc;

    // --- wave / fragment assignment ---
    const int lane = tid & 63;
    const int wave = tid >> 6;
    const int wm = wave >> 2;         // 0..1: token half (32 rows each)
    const int wn = wave & 3;          // 0..3: expert quarter (64 experts)
    const int l16 = lane & 15;
    const int quad = lane >> 4;

    f32x4 acc[2][4];
    #pragma unroll
    for (int i = 0; i < 2; i++)
        #pragma unroll
        for (int j = 0; j < 4; j++) acc[i][j] = (f32x4){0.f, 0.f, 0.f, 0.f};

    // prefetch tile 0 into registers
    float4 a0 = *(const float4*)(xa);
    uint4 h0 = *(const uint4*)(wh0);
    uint4 h1 = *(const uint4*)(wh1);
    uint4 l0 = *(const uint4*)(wl0);
    uint4 l1 = *(const uint4*)(wl1);

    for (int it = 0; it < KITERS; ++it) {
        __syncthreads();   // all waves done reading LDS of previous tile
        // --- split A (fp32 -> fp16 hi/lo) + store; store B planes ---
        {
            ushort4 h, l;
            _Float16 t;
            t = (_Float16)a0.x; h.x = f16_bits(t); l.x = f16_bits((_Float16)(a0.x - (float)t));
            t = (_Float16)a0.y; h.y = f16_bits(t); l.y = f16_bits((_Float16)(a0.y - (float)t));
            t = (_Float16)a0.z; h.z = f16_bits(t); l.z = f16_bits((_Float16)(a0.z - (float)t));
            t = (_Float16)a0.w; h.w = f16_bits(t); l.w = f16_bits((_Float16)(a0.w - (float)t));
            *(ushort4*)&Ahi[ar * KP + ac] = h;
            *(ushort4*)&Alo[ar * KP + ac] = l;
        }
        *(uint4*)&Bhi[br * KP + bc] = h0;
        *(uint4*)&Bhi[(br + 128) * KP + bc] = h1;
        *(uint4*)&Blo[br * KP + bc] = l0;
        *(uint4*)&Blo[(br + 128) * KP + bc] = l1;
        __syncthreads();

        // --- prefetch next tile (hidden under ds_read + MFMA section) ---
        if (it + 1 < KITERS) {
            const int ko = (it + 1) * BK;
            a0 = *(const float4*)(xa + ko);
            h0 = *(const uint4*)(wh0 + ko);
            h1 = *(const uint4*)(wh1 + ko);
            l0 = *(const uint4*)(wl0 + ko);
            l1 = *(const uint4*)(wl1 + ko);
        }

        // --- LDS -> fragments (ds_read_b128, 80B row stride) ---
        f16x8 fah[2], fal[2], fbh[4], fbl[4];
        #pragma unroll
        for (int i = 0; i < 2; i++) {
            const int mrow = wm * 32 + i * 16 + l16;
            fah[i] = *(const f16x8*)&Ahi[mrow * KP + quad * 8];
            fal[i] = *(const f16x8*)&Alo[mrow * KP + quad * 8];
        }
        #pragma unroll
        for (int j = 0; j < 4; j++) {
            const int nrow = wn * 64 + j * 16 + l16;
            fbh[j] = *(const f16x8*)&Bhi[nrow * KP + quad * 8];
            fbl[j] = *(const f16x8*)&Blo[nrow * KP + quad * 8];
        }
        // --- 3-term split-fp16 MFMA: hh + hl + lh (ll term is O(2^-24)) ---
        #pragma unroll
        for (int i = 0; i < 2; i++)
            #pragma unroll
            for (int j = 0; j < 4; j++) {
                acc[i][j] = __builtin_amdgcn_mfma_f32_16x16x32_f16(fah[i], fbh[j], acc[i][j], 0, 0, 0);
                acc[i][j] = __builtin_amdgcn_mfma_f32_16x16x32_f16(fah[i], fbl[j], acc[i][j], 0, 0, 0);
                acc[i][j] = __builtin_amdgcn_mfma_f32_16x16x32_f16(fal[i], fbh[j], acc[i][j], 0, 0, 0);
            }
    }

    // --- epilogue: biased sigmoid scores -> LDS (single pass), fused routing ---
    float bv[4];
    #pragma unroll
    for (int j = 0; j < 4; j++) bv[j] = bias[wn * 64 + j * 16 + l16];

    __syncthreads();   // staging reads complete before Sc alias overwrite
    #pragma unroll
    for (int i = 0; i < 2; i++)
        #pragma unroll
        for (int j = 0; j < 4; j++)
            #pragma unroll
            for (int r = 0; r < 4; r++) {
                const int trow = wm * 32 + i * 16 + quad * 4 + r;    // 0..63
                const int e = wn * 64 + j * 16 + l16;                // 0..255
                const float logit = acc[i][j][r] * INV_W_SCALE;
                const float s = 1.f / (1.f + expf(-logit));
                Sc[trow * N_EXPERTS + e] = s + bv[j];                // BIASED
            }
    __syncthreads();

    if (tid < 64) {    // one wave routes 64 tokens; lane-staggered LDS reads
        const float* row = Sc + tid * N_EXPERTS;

        // group score = sum of top-2 biased (matches jax order: m1+m2)
        float gs[N_GROUPS];
        #pragma unroll
        for (int g = 0; g < N_GROUPS; g++) {
            float m1 = -INFINITY, m2 = -INFINITY;
            #pragma unroll
            for (int jj = 0; jj < EPG; jj++) {
                const float v = row[g * EPG + ((tid + jj) & (EPG - 1))];
                if (v > m1) { m2 = m1; m1 = v; }
                else if (v > m2) { m2 = v; }
            }
            gs[g] = m1 + m2;
        }
        // keep top-4 groups (jax tie-break: lower index wins)
        unsigned keep = 0;
        #pragma unroll
        for (int g = 0; g < N_GROUPS; g++) {
            int cnt = 0;
            #pragma unroll
            for (int h = 0; h < N_GROUPS; h++)
                if (gs[h] > gs[g] || (gs[h] == gs[g] && h < g)) cnt++;
            if (cnt < TOPK_GROUPS) keep |= (1u << g);
        }
        // top-8 experts within kept groups; comparator (v desc, idx asc)
        // makes result independent of staggered scan order
        float tv[TOPK]; int ti[TOPK];
        #pragma unroll
        for (int i = 0; i < TOPK; i++) { tv[i] = -INFINITY; ti[i] = 0x7fffffff; }
        for (int g = 0; g < N_GROUPS; g++) {
            if (!(keep & (1u << g))) continue;
            #pragma unroll 4
            for (int jj = 0; jj < EPG; jj++) {
                const int e = g * EPG + ((tid + jj) & (EPG - 1));
                const float v = row[e];
                if (v > tv[TOPK - 1] || (v == tv[TOPK - 1] && e < ti[TOPK - 1])) {
                    float cv = v; int ce = e;
                    #pragma unroll
                    for (int s = 0; s < TOPK; s++) {
                        const bool b = (cv > tv[s]) || (cv == tv[s] && ce < ti[s]);
                        if (b) {
                            const float t1 = tv[s]; tv[s] = cv; cv = t1;
                            const int t2 = ti[s]; ti[s] = ce; ce = t2;
                        }
                    }
                }
            }
        }
        // weights from RAW scores (biased - bias), normalize, scale
        float w[TOPK], sum = 0.f;
        #pragma unroll
        for (int i = 0; i < TOPK; i++) {
            w[i] = row[ti[i]] - bias[ti[i]];
            sum += w[i];
        }
        const float scale = ROUTE_SCALE / fmaxf(sum, 1e-10f);
        const size_t t = (size_t)m0 + tid;
        #pragma unroll
        for (int i = 0; i < TOPK; i++) {
            out_w[t * TOPK + i] = w[i] * scale;
            out_i[t * TOPK + i] = (float)ti[i];
        }
    }
}

extern "C" void kernel_launch(void* const* d_in, const int* in_sizes, int n_in,
                              void* d_out, int out_size, void* d_ws, size_t ws_size,
                              hipStream_t stream)
{
    const float* x = (const float*)d_in[0];     // (T, D)
    const float* w = (const float*)d_in[1];     // (E, D)
    const float* b = (const float*)d_in[2];     // (E,)

    u16* whi = (u16*)d_ws;                      // (E, D) fp16 hi plane, 1 MB
    u16* wlo = whi + (size_t)N_EXPERTS * DIM;   // (E, D) fp16 lo plane, 1 MB

    float* out_w = (float*)d_out;                              // (T, 8)
    float* out_i = (float*)d_out + (size_t)T_TOKENS * TOPK;    // (T, 8) as fp32

    convert_w<<<(N_EXPERTS * DIM) / 256, 256, 0, stream>>>(w, whi, wlo);
    fused_gate<<<T_TOKENS / BM, 512, 0, stream>>>(x, whi, wlo, b, out_w, out_i);
}